// Round 3
// baseline (418.641 us; speedup 1.0000x reference)
//
#include <hip/hip_runtime.h>
#include <stdint.h>

// GCN 2-layer, N=100000, E=1.6M, 128->32->16, f32.
// NOTE: harness stages integer inputs as int32 (NOT the reference's int64).
// CSR-by-dst build (histogram + 3-kernel scan + atomic-return fill with
// precomputed per-edge norm), then atomic-free gather aggregation for both
// layers. Self-loop contribution handled analytically in the agg init.
//
// ws layout (256B-aligned chunks):
//   rowptr[N+1] u32 | cnt[N] u32 | cursor[N] u32 | partial[512] u32 |
//   dinv[N] f32 | adj[E] int2{src, norm-bits} | h1/h2[32N] f32 | agg1[32N] f32
// total ~40.0 MB.

#define TPB 256

__global__ void k_zero2(unsigned int* __restrict__ a, unsigned int* __restrict__ b, int n) {
    int i = blockIdx.x * blockDim.x + threadIdx.x;
    if (i < n) { a[i] = 0u; b[i] = 0u; }
}

// ---------- degree histogram (real edges only; self-loop added analytically)
__global__ void k_count(const int* __restrict__ dst, unsigned int* __restrict__ cnt, int E) {
    int stride = gridDim.x * blockDim.x;
    for (int i = blockIdx.x * blockDim.x + threadIdx.x; i < E; i += stride)
        atomicAdd(&cnt[(unsigned int)dst[i]], 1u);
}

__global__ void k_dinv(const unsigned int* __restrict__ cnt, float* __restrict__ dinv, int n) {
    int i = blockIdx.x * blockDim.x + threadIdx.x;
    if (i < n) dinv[i] = rsqrtf(1.0f + (float)cnt[i]);   // +1 = self-loop
}

// ---------- exclusive scan of cnt -> rowptr (3 kernels; NB <= 512)
__global__ void k_blocksums(const unsigned int* __restrict__ cnt, unsigned int* __restrict__ partial, int n) {
    __shared__ unsigned int sm[TPB];
    int i = blockIdx.x * TPB + threadIdx.x;
    sm[threadIdx.x] = (i < n) ? cnt[i] : 0u;
    __syncthreads();
    for (int off = TPB / 2; off > 0; off >>= 1) {
        if (threadIdx.x < off) sm[threadIdx.x] += sm[threadIdx.x + off];
        __syncthreads();
    }
    if (threadIdx.x == 0) partial[blockIdx.x] = sm[0];
}

__global__ void k_scanpartials(unsigned int* __restrict__ partial, int nb) {
    __shared__ unsigned int sm[512];
    int t = threadIdx.x;
    unsigned int v = (t < nb) ? partial[t] : 0u;
    sm[t] = v;
    __syncthreads();
    for (int off = 1; off < 512; off <<= 1) {
        unsigned int add = (t >= off) ? sm[t - off] : 0u;
        __syncthreads();
        sm[t] += add;
        __syncthreads();
    }
    if (t < nb) partial[t] = sm[t] - v;   // exclusive
}

__global__ void k_rowptr(const unsigned int* __restrict__ cnt, const unsigned int* __restrict__ partial,
                         unsigned int* __restrict__ rowptr, int n, int E) {
    __shared__ unsigned int sm[TPB];
    int t = threadIdx.x;
    int i = blockIdx.x * TPB + t;
    unsigned int v = (i < n) ? cnt[i] : 0u;
    sm[t] = v;
    __syncthreads();
    for (int off = 1; off < TPB; off <<= 1) {
        unsigned int add = (t >= off) ? sm[t - off] : 0u;
        __syncthreads();
        sm[t] += add;
        __syncthreads();
    }
    if (i < n) rowptr[i] = partial[blockIdx.x] + sm[t] - v;  // exclusive
    if (i == n - 1) rowptr[n] = (unsigned int)E;
}

// ---------- CSR fill: adj[pos] = {src, bits(dinv[s]*dinv[d])}
__global__ void k_fill(const int* __restrict__ ei, const float* __restrict__ dinv,
                       const unsigned int* __restrict__ rowptr, unsigned int* __restrict__ cursor,
                       int2* __restrict__ adj, int E) {
    const int* srcp = ei;
    const int* dstp = ei + E;
    int stride = gridDim.x * blockDim.x;
    for (int i = blockIdx.x * blockDim.x + threadIdx.x; i < E; i += stride) {
        int s = srcp[i], d = dstp[i];
        unsigned int pos = rowptr[d] + atomicAdd(&cursor[d], 1u);
        adj[pos] = make_int2(s, __float_as_int(dinv[s] * dinv[d]));
    }
}

// ---------- h1 = x @ W1 (32 lanes share a row; W1 is L1-resident)
__global__ void k_gemm1(const float* __restrict__ x, const float* __restrict__ W1,
                        float* __restrict__ h1, int n) {
    int t = blockIdx.x * blockDim.x + threadIdx.x;
    if (t >= n * 32) return;
    int row = t >> 5, j = t & 31;
    const float4* xr = (const float4*)(x + (size_t)row * 128);
    float acc = 0.f;
#pragma unroll 8
    for (int k4 = 0; k4 < 32; ++k4) {
        float4 xv = xr[k4];
        int k = k4 * 4;
        acc = fmaf(xv.x, W1[(k + 0) * 32 + j], acc);
        acc = fmaf(xv.y, W1[(k + 1) * 32 + j], acc);
        acc = fmaf(xv.z, W1[(k + 2) * 32 + j], acc);
        acc = fmaf(xv.w, W1[(k + 3) * 32 + j], acc);
    }
    h1[t] = acc;
}

// ---------- agg1[n] = h1[n]*dinv[n]^2 + sum_{e in CSR[n]} h1[src_e]*norm_e
// 8 lanes per node, float4 per lane (whole 128B h1 row gathered per edge).
__global__ void k_agg1(const float* __restrict__ h1, const float* __restrict__ dinv,
                       const unsigned int* __restrict__ rowptr, const int2* __restrict__ adj,
                       float* __restrict__ agg1, int n) {
    int t = blockIdx.x * blockDim.x + threadIdx.x;
    if (t >= n * 8) return;
    int node = t >> 3, c4 = (t & 7) * 4;
    float di = dinv[node];
    float di2 = di * di;
    float4 acc = *(const float4*)(h1 + (size_t)node * 32 + c4);
    acc.x *= di2; acc.y *= di2; acc.z *= di2; acc.w *= di2;
    unsigned int e1 = rowptr[node + 1];
    for (unsigned int e = rowptr[node]; e < e1; ++e) {
        int2 a = adj[e];
        float nrm = __int_as_float(a.y);
        float4 hv = *(const float4*)(h1 + (size_t)a.x * 32 + c4);
        acc.x = fmaf(hv.x, nrm, acc.x);
        acc.y = fmaf(hv.y, nrm, acc.y);
        acc.z = fmaf(hv.z, nrm, acc.z);
        acc.w = fmaf(hv.w, nrm, acc.w);
    }
    *(float4*)(agg1 + (size_t)node * 32 + c4) = acc;
}

// ---------- h2 = relu(agg1 + b1) @ W2 (raw, no bias/self-loop yet)
__global__ void k_gemm2(const float* __restrict__ agg1, const float* __restrict__ b1,
                        const float* __restrict__ W2, float* __restrict__ h2, int n) {
    int t = blockIdx.x * blockDim.x + threadIdx.x;
    if (t >= n * 16) return;
    int row = t >> 4, j = t & 15;
    const float4* ar = (const float4*)(agg1 + (size_t)row * 32);
    float acc = 0.f;
#pragma unroll
    for (int k4 = 0; k4 < 8; ++k4) {
        float4 av = ar[k4];
        int k = k4 * 4;
        float v0 = fmaxf(av.x + b1[k + 0], 0.f);
        float v1 = fmaxf(av.y + b1[k + 1], 0.f);
        float v2 = fmaxf(av.z + b1[k + 2], 0.f);
        float v3 = fmaxf(av.w + b1[k + 3], 0.f);
        acc = fmaf(v0, W2[(k + 0) * 16 + j], acc);
        acc = fmaf(v1, W2[(k + 1) * 16 + j], acc);
        acc = fmaf(v2, W2[(k + 2) * 16 + j], acc);
        acc = fmaf(v3, W2[(k + 3) * 16 + j], acc);
    }
    h2[t] = acc;
}

// ---------- out[n] = h2[n]*dinv[n]^2 + b2 + sum_{e} h2[src_e]*norm_e
// 4 lanes per node, float4 per lane (whole 64B h2 row per edge).
__global__ void k_agg2(const float* __restrict__ h2, const float* __restrict__ dinv,
                       const float* __restrict__ b2,
                       const unsigned int* __restrict__ rowptr, const int2* __restrict__ adj,
                       float* __restrict__ out, int n) {
    int t = blockIdx.x * blockDim.x + threadIdx.x;
    if (t >= n * 4) return;
    int node = t >> 2, c4 = (t & 3) * 4;
    float di = dinv[node];
    float di2 = di * di;
    float4 hv0 = *(const float4*)(h2 + (size_t)node * 16 + c4);
    float4 bv = *(const float4*)(b2 + c4);
    float4 acc = make_float4(fmaf(hv0.x, di2, bv.x), fmaf(hv0.y, di2, bv.y),
                             fmaf(hv0.z, di2, bv.z), fmaf(hv0.w, di2, bv.w));
    unsigned int e1 = rowptr[node + 1];
    for (unsigned int e = rowptr[node]; e < e1; ++e) {
        int2 a = adj[e];
        float nrm = __int_as_float(a.y);
        float4 hv = *(const float4*)(h2 + (size_t)a.x * 16 + c4);
        acc.x = fmaf(hv.x, nrm, acc.x);
        acc.y = fmaf(hv.y, nrm, acc.y);
        acc.z = fmaf(hv.z, nrm, acc.z);
        acc.w = fmaf(hv.w, nrm, acc.w);
    }
    *(float4*)(out + (size_t)node * 16 + c4) = acc;
}

static inline char* align256(char* p) {
    return (char*)(((uintptr_t)p + 255) & ~(uintptr_t)255);
}

extern "C" void kernel_launch(void* const* d_in, const int* in_sizes, int n_in,
                              void* d_out, int out_size, void* d_ws, size_t ws_size,
                              hipStream_t stream) {
    const float* x  = (const float*)d_in[0];
    const int*   ei = (const int*)d_in[1];     // int32! harness downcasts int64
    const float* W1 = (const float*)d_in[2];
    const float* b1 = (const float*)d_in[3];
    const float* W2 = (const float*)d_in[4];
    const float* b2 = (const float*)d_in[5];
    float*       out = (float*)d_out;

    int N = in_sizes[0] / 128;
    int E = in_sizes[1] / 2;

    char* p = (char*)d_ws;
    unsigned int* rowptr  = (unsigned int*)p;  p = align256(p + (size_t)(N + 1) * 4);
    unsigned int* cnt     = (unsigned int*)p;  p = align256(p + (size_t)N * 4);
    unsigned int* cursor  = (unsigned int*)p;  p = align256(p + (size_t)N * 4);
    unsigned int* partial = (unsigned int*)p;  p = align256(p + 512 * 4);
    float*        dinv    = (float*)p;         p = align256(p + (size_t)N * 4);
    int2*         adj     = (int2*)p;          p = align256(p + (size_t)E * 8);
    float*        h1      = (float*)p;         p = align256(p + (size_t)N * 32 * 4);
    float*        agg1    = (float*)p;         /* + 32N*4; h2 aliases h1 (dead after k_agg1) */
    float*        h2      = h1;

    int gN = (N + TPB - 1) / TPB;   // 391 blocks; scan supports <= 512
    int NB = gN;

    k_zero2        <<<gN,   TPB, 0, stream>>>(cnt, cursor, N);
    k_count        <<<2048, TPB, 0, stream>>>(ei + E, cnt, E);
    k_dinv         <<<gN,   TPB, 0, stream>>>(cnt, dinv, N);
    k_blocksums    <<<NB,   TPB, 0, stream>>>(cnt, partial, N);
    k_scanpartials <<<1,    512, 0, stream>>>(partial, NB);
    k_rowptr       <<<NB,   TPB, 0, stream>>>(cnt, partial, rowptr, N, E);
    k_fill         <<<2048, TPB, 0, stream>>>(ei, dinv, rowptr, cursor, adj, E);

    k_gemm1 <<<(N * 32 + TPB - 1) / TPB, TPB, 0, stream>>>(x, W1, h1, N);
    k_agg1  <<<(N * 8  + TPB - 1) / TPB, TPB, 0, stream>>>(h1, dinv, rowptr, adj, agg1, N);
    k_gemm2 <<<(N * 16 + TPB - 1) / TPB, TPB, 0, stream>>>(agg1, b1, W2, h2, N);
    k_agg2  <<<(N * 4  + TPB - 1) / TPB, TPB, 0, stream>>>(h2, dinv, b2, rowptr, adj, out, N);
}

// Round 5
// 358.468 us; speedup vs baseline: 1.1679x; 1.1679x over previous
//
#include <hip/hip_runtime.h>
#include <stdint.h>

// GCN 2-layer, N=100000, E=1.6M, 128->32->16, f32.
// edge_index arrives as int32 (harness downcasts the reference's int64).
// CSR-by-dst build + atomic-free gather aggregation. Self-loops analytic.
// R3: LDS-tiled register-blocked gemm1/gemm2 (old gemm1 was vmem-issue-bound:
//     105us at 10% VALUBusy / 4% HBM).
// R4: fix k_gemm2 W2 staging (512 elems with 256 threads needs 2 iterations;
//     the t<512 guard staged only half of W2^T -> poisoned LDS reads).

#define TPB 256

__global__ void k_zero2(unsigned int* __restrict__ a, unsigned int* __restrict__ b, int n) {
    int i = blockIdx.x * blockDim.x + threadIdx.x;
    if (i < n) { a[i] = 0u; b[i] = 0u; }
}

// ---------- degree histogram (real edges only)
__global__ void k_count(const int* __restrict__ dst, unsigned int* __restrict__ cnt, int E) {
    int stride = gridDim.x * blockDim.x;
    for (int i = blockIdx.x * blockDim.x + threadIdx.x; i < E; i += stride)
        atomicAdd(&cnt[(unsigned int)dst[i]], 1u);
}

__global__ void k_dinv(const unsigned int* __restrict__ cnt, float* __restrict__ dinv, int n) {
    int i = blockIdx.x * blockDim.x + threadIdx.x;
    if (i < n) dinv[i] = rsqrtf(1.0f + (float)cnt[i]);   // +1 = self-loop
}

// ---------- exclusive scan of cnt -> rowptr (3 kernels; NB <= 512)
__global__ void k_blocksums(const unsigned int* __restrict__ cnt, unsigned int* __restrict__ partial, int n) {
    __shared__ unsigned int sm[TPB];
    int i = blockIdx.x * TPB + threadIdx.x;
    sm[threadIdx.x] = (i < n) ? cnt[i] : 0u;
    __syncthreads();
    for (int off = TPB / 2; off > 0; off >>= 1) {
        if (threadIdx.x < off) sm[threadIdx.x] += sm[threadIdx.x + off];
        __syncthreads();
    }
    if (threadIdx.x == 0) partial[blockIdx.x] = sm[0];
}

__global__ void k_scanpartials(unsigned int* __restrict__ partial, int nb) {
    __shared__ unsigned int sm[512];
    int t = threadIdx.x;
    unsigned int v = (t < nb) ? partial[t] : 0u;
    sm[t] = v;
    __syncthreads();
    for (int off = 1; off < 512; off <<= 1) {
        unsigned int add = (t >= off) ? sm[t - off] : 0u;
        __syncthreads();
        sm[t] += add;
        __syncthreads();
    }
    if (t < nb) partial[t] = sm[t] - v;   // exclusive
}

__global__ void k_rowptr(const unsigned int* __restrict__ cnt, const unsigned int* __restrict__ partial,
                         unsigned int* __restrict__ rowptr, int n, int E) {
    __shared__ unsigned int sm[TPB];
    int t = threadIdx.x;
    int i = blockIdx.x * TPB + t;
    unsigned int v = (i < n) ? cnt[i] : 0u;
    sm[t] = v;
    __syncthreads();
    for (int off = 1; off < TPB; off <<= 1) {
        unsigned int add = (t >= off) ? sm[t - off] : 0u;
        __syncthreads();
        sm[t] += add;
        __syncthreads();
    }
    if (i < n) rowptr[i] = partial[blockIdx.x] + sm[t] - v;  // exclusive
    if (i == n - 1) rowptr[n] = (unsigned int)E;
}

// ---------- CSR fill: adj[pos] = {src, bits(dinv[s]*dinv[d])}
__global__ void k_fill(const int* __restrict__ ei, const float* __restrict__ dinv,
                       const unsigned int* __restrict__ rowptr, unsigned int* __restrict__ cursor,
                       int2* __restrict__ adj, int E) {
    const int* srcp = ei;
    const int* dstp = ei + E;
    int stride = gridDim.x * blockDim.x;
    for (int i = blockIdx.x * blockDim.x + threadIdx.x; i < E; i += stride) {
        int s = srcp[i], d = dstp[i];
        unsigned int pos = rowptr[d] + atomicAdd(&cursor[d], 1u);
        adj[pos] = make_int2(s, __float_as_int(dinv[s] * dinv[d]));
    }
}

// ---------- gemm1: h1 = x @ W1.  64 rows/block, LDS tile, 8 rows x 1 col per thread.
__global__ __launch_bounds__(TPB) void k_gemm1(const float* __restrict__ x, const float* __restrict__ W1,
                                               float* __restrict__ h1, int n) {
    __shared__ float4 smx4[64 * 32];      // 64 rows x 128 floats = 32 KB
    __shared__ float4 smw4[32 * 33];      // W1^T [j][k], rows padded to 132 floats
    float* smw = (float*)smw4;
    int t = threadIdx.x;
    int row0 = blockIdx.x * 64;

    // stage W1^T: W1[k*32+j] -> smw[j*132+k]   (4096 = 16*256 elements)
#pragma unroll
    for (int it = 0; it < 16; ++it) {
        int idx = it * TPB + t;
        int k = idx >> 5, j = idx & 31;
        smw[j * 132 + k] = W1[idx];
    }
    // stage x tile: 2048 float4 (coalesced), zero-fill OOB tail
    const float4* x4 = (const float4*)x;
    int lim = n * 32;
#pragma unroll
    for (int it = 0; it < 8; ++it) {
        int fo = it * TPB + t;            // [0,2048)
        int gi = row0 * 32 + fo;
        smx4[fo] = (gi < lim) ? x4[gi] : make_float4(0.f, 0.f, 0.f, 0.f);
    }
    __syncthreads();

    int j = t & 31, rb = (t >> 5) * 8;
    float acc[8] = {0.f, 0.f, 0.f, 0.f, 0.f, 0.f, 0.f, 0.f};
#pragma unroll 4
    for (int k4 = 0; k4 < 32; ++k4) {
        float4 wv = smw4[j * 33 + k4];
#pragma unroll
        for (int i = 0; i < 8; ++i) {
            float4 xv = smx4[(rb + i) * 32 + k4];
            acc[i] = fmaf(xv.x, wv.x, acc[i]);
            acc[i] = fmaf(xv.y, wv.y, acc[i]);
            acc[i] = fmaf(xv.z, wv.z, acc[i]);
            acc[i] = fmaf(xv.w, wv.w, acc[i]);
        }
    }
#pragma unroll
    for (int i = 0; i < 8; ++i) {
        int row = row0 + rb + i;
        if (row < n) h1[(size_t)row * 32 + j] = acc[i];
    }
}

// ---------- agg1[n] = h1[n]*dinv[n]^2 + sum_{e in CSR[n]} h1[src_e]*norm_e
__global__ void k_agg1(const float* __restrict__ h1, const float* __restrict__ dinv,
                       const unsigned int* __restrict__ rowptr, const int2* __restrict__ adj,
                       float* __restrict__ agg1, int n) {
    int t = blockIdx.x * blockDim.x + threadIdx.x;
    if (t >= n * 8) return;
    int node = t >> 3, c4 = (t & 7) * 4;
    float di = dinv[node];
    float di2 = di * di;
    float4 acc = *(const float4*)(h1 + (size_t)node * 32 + c4);
    acc.x *= di2; acc.y *= di2; acc.z *= di2; acc.w *= di2;
    unsigned int e1 = rowptr[node + 1];
    for (unsigned int e = rowptr[node]; e < e1; ++e) {
        int2 a = adj[e];
        float nrm = __int_as_float(a.y);
        float4 hv = *(const float4*)(h1 + (size_t)a.x * 32 + c4);
        acc.x = fmaf(hv.x, nrm, acc.x);
        acc.y = fmaf(hv.y, nrm, acc.y);
        acc.z = fmaf(hv.z, nrm, acc.z);
        acc.w = fmaf(hv.w, nrm, acc.w);
    }
    *(float4*)(agg1 + (size_t)node * 32 + c4) = acc;
}

// ---------- gemm2: h2 = relu(agg1 + b1) @ W2.  128 rows/block, bias+relu fused into staging.
__global__ __launch_bounds__(TPB) void k_gemm2(const float* __restrict__ agg1, const float* __restrict__ b1,
                                               const float* __restrict__ W2, float* __restrict__ h2, int n) {
    __shared__ float4 sma4[128 * 8];      // 128 rows x 32 floats = 16 KB (post-relu)
    __shared__ float4 smw24[16 * 9];      // W2^T [j][k], rows padded to 36 floats
    float* smw2 = (float*)smw24;
    int t = threadIdx.x;
    int row0 = blockIdx.x * 128;

    // stage W2^T: W2[k*16+j] -> smw2[j*36+k]   (512 = 2*256 elements; R4 fix)
#pragma unroll
    for (int it = 0; it < 2; ++it) {
        int idx = it * TPB + t;
        int k = idx >> 4, j = idx & 15;
        smw2[j * 36 + k] = W2[idx];
    }
    const float4* a4 = (const float4*)agg1;
    const float4* b14 = (const float4*)b1;
    int lim = n * 8;
#pragma unroll
    for (int it = 0; it < 4; ++it) {
        int fo = it * TPB + t;            // [0,1024)
        int gi = row0 * 8 + fo;
        float4 v = (gi < lim) ? a4[gi] : make_float4(0.f, 0.f, 0.f, 0.f);
        float4 b = b14[fo & 7];
        v.x = fmaxf(v.x + b.x, 0.f);
        v.y = fmaxf(v.y + b.y, 0.f);
        v.z = fmaxf(v.z + b.z, 0.f);
        v.w = fmaxf(v.w + b.w, 0.f);
        sma4[fo] = v;
    }
    __syncthreads();

    int j = t & 15, rb = (t >> 4) * 8;
    float acc[8] = {0.f, 0.f, 0.f, 0.f, 0.f, 0.f, 0.f, 0.f};
#pragma unroll
    for (int k4 = 0; k4 < 8; ++k4) {
        float4 wv = smw24[j * 9 + k4];
#pragma unroll
        for (int i = 0; i < 8; ++i) {
            float4 xv = sma4[(rb + i) * 8 + k4];
            acc[i] = fmaf(xv.x, wv.x, acc[i]);
            acc[i] = fmaf(xv.y, wv.y, acc[i]);
            acc[i] = fmaf(xv.z, wv.z, acc[i]);
            acc[i] = fmaf(xv.w, wv.w, acc[i]);
        }
    }
#pragma unroll
    for (int i = 0; i < 8; ++i) {
        int row = row0 + rb + i;
        if (row < n) h2[(size_t)row * 16 + j] = acc[i];
    }
}

// ---------- out[n] = h2[n]*dinv[n]^2 + b2 + sum_{e} h2[src_e]*norm_e
__global__ void k_agg2(const float* __restrict__ h2, const float* __restrict__ dinv,
                       const float* __restrict__ b2,
                       const unsigned int* __restrict__ rowptr, const int2* __restrict__ adj,
                       float* __restrict__ out, int n) {
    int t = blockIdx.x * blockDim.x + threadIdx.x;
    if (t >= n * 4) return;
    int node = t >> 2, c4 = (t & 3) * 4;
    float di = dinv[node];
    float di2 = di * di;
    float4 hv0 = *(const float4*)(h2 + (size_t)node * 16 + c4);
    float4 bv = *(const float4*)(b2 + c4);
    float4 acc = make_float4(fmaf(hv0.x, di2, bv.x), fmaf(hv0.y, di2, bv.y),
                             fmaf(hv0.z, di2, bv.z), fmaf(hv0.w, di2, bv.w));
    unsigned int e1 = rowptr[node + 1];
    for (unsigned int e = rowptr[node]; e < e1; ++e) {
        int2 a = adj[e];
        float nrm = __int_as_float(a.y);
        float4 hv = *(const float4*)(h2 + (size_t)a.x * 16 + c4);
        acc.x = fmaf(hv.x, nrm, acc.x);
        acc.y = fmaf(hv.y, nrm, acc.y);
        acc.z = fmaf(hv.z, nrm, acc.z);
        acc.w = fmaf(hv.w, nrm, acc.w);
    }
    *(float4*)(out + (size_t)node * 16 + c4) = acc;
}

static inline char* align256(char* p) {
    return (char*)(((uintptr_t)p + 255) & ~(uintptr_t)255);
}

extern "C" void kernel_launch(void* const* d_in, const int* in_sizes, int n_in,
                              void* d_out, int out_size, void* d_ws, size_t ws_size,
                              hipStream_t stream) {
    const float* x  = (const float*)d_in[0];
    const int*   ei = (const int*)d_in[1];     // int32 (harness downcasts int64)
    const float* W1 = (const float*)d_in[2];
    const float* b1 = (const float*)d_in[3];
    const float* W2 = (const float*)d_in[4];
    const float* b2 = (const float*)d_in[5];
    float*       out = (float*)d_out;

    int N = in_sizes[0] / 128;
    int E = in_sizes[1] / 2;

    char* p = (char*)d_ws;
    unsigned int* rowptr  = (unsigned int*)p;  p = align256(p + (size_t)(N + 1) * 4);
    unsigned int* cnt     = (unsigned int*)p;  p = align256(p + (size_t)N * 4);
    unsigned int* cursor  = (unsigned int*)p;  p = align256(p + (size_t)N * 4);
    unsigned int* partial = (unsigned int*)p;  p = align256(p + 512 * 4);
    float*        dinv    = (float*)p;         p = align256(p + (size_t)N * 4);
    int2*         adj     = (int2*)p;          p = align256(p + (size_t)E * 8);
    float*        h1      = (float*)p;         p = align256(p + (size_t)N * 32 * 4);
    float*        agg1    = (float*)p;         /* + 32N*4; h2 aliases h1 (dead after k_agg1) */
    float*        h2      = h1;

    int gN = (N + TPB - 1) / TPB;   // 391 blocks; scan supports <= 512
    int NB = gN;

    k_zero2        <<<gN,   TPB, 0, stream>>>(cnt, cursor, N);
    k_count        <<<2048, TPB, 0, stream>>>(ei + E, cnt, E);
    k_dinv         <<<gN,   TPB, 0, stream>>>(cnt, dinv, N);
    k_blocksums    <<<NB,   TPB, 0, stream>>>(cnt, partial, N);
    k_scanpartials <<<1,    512, 0, stream>>>(partial, NB);
    k_rowptr       <<<NB,   TPB, 0, stream>>>(cnt, partial, rowptr, N, E);
    k_fill         <<<2048, TPB, 0, stream>>>(ei, dinv, rowptr, cursor, adj, E);

    k_gemm1 <<<(N + 63) / 64,          TPB, 0, stream>>>(x, W1, h1, N);
    k_agg1  <<<(N * 8 + TPB - 1) / TPB, TPB, 0, stream>>>(h1, dinv, rowptr, adj, agg1, N);
    k_gemm2 <<<(N + 127) / 128,        TPB, 0, stream>>>(agg1, b1, W2, h2, N);
    k_agg2  <<<(N * 4 + TPB - 1) / TPB, TPB, 0, stream>>>(h2, dinv, b2, rowptr, adj, out, N);
}